// Round 5
// baseline (1198.186 us; speedup 1.0000x reference)
//
#include <hip/hip_runtime.h>
#include <hip/hip_bf16.h>
#include <stdint.h>

typedef unsigned short u16;
typedef __bf16 bf16_8 __attribute__((ext_vector_type(8)));
typedef float f32x4 __attribute__((ext_vector_type(4)));

#define SEQ 2048
#define DIM 4096
#define NH 32
#define NKV 8
#define HD 128
// 1/sqrt(128) * log2(e)  -- exp2-based softmax, scale folded into Q epilogue
#define QSCALE_LOG2E 0.12753785222167917f

__device__ inline u16 f2bf(float f) {
    unsigned int u = __float_as_uint(f);
    unsigned int r = (u + 0x7fffu + ((u >> 16) & 1u)) >> 16;
    return (u16)r;
}

__device__ inline void async16(const void* g, void* l) {
    __builtin_amdgcn_global_load_lds(
        (const __attribute__((address_space(1))) void*)g,
        (__attribute__((address_space(3))) void*)l, 16, 0, 0);
}

// ---------------- fused fp32 -> bf16 cast of all 5 tensors ----------------
__global__ __launch_bounds__(256) void cast_all(const float* __restrict__ x,
                                                const float* __restrict__ wq,
                                                const float* __restrict__ wk,
                                                const float* __restrict__ wv,
                                                const float* __restrict__ wo,
                                                u16* __restrict__ dst) {
    size_t i4 = (size_t)blockIdx.x * 256 + threadIdx.x;  // float4 group index
    size_t e = i4 * 4;                                   // element index
    const float* src;
    size_t off;  // segment start (elements)
    if (e < 8388608ull)       { src = x;  off = 0; }
    else if (e < 25165824ull) { src = wq; off = 8388608ull; }
    else if (e < 29360128ull) { src = wk; off = 25165824ull; }
    else if (e < 33554432ull) { src = wv; off = 29360128ull; }
    else                      { src = wo; off = 33554432ull; }
    float4 v = ((const float4*)src)[i4 - off / 4];
    ushort4 o;
    o.x = f2bf(v.x); o.y = f2bf(v.y); o.z = f2bf(v.z); o.w = f2bf(v.w);
    ((ushort4*)dst)[i4] = o;
}

// ======== reg-staged double-buffered GEMM: C = A[M,K] * B[N,K]^T (bf16) =====
// 128x128 tile, BK=32, 256 threads (4 waves, 2x2), wave tile 64x64, acc[4][4].
// Staging is global_load_dwordx4 -> VGPR -> ds_write_b128 (T14): the load->use
// dependency is register-carried, so the compiler emits PRECISE counted vmcnt
// (no LDS-DMA alias conservatism as with global_load_lds) and prefetch loads
// for tile t+2 provably stay in flight across barriers.  Raw s_barrier with
// only lgkmcnt(0) before it (ds_write visibility); no vmcnt at barriers.
// LDS rows padded to 40 u16 (80 B): bank-quad = (5*l16+quad)%8 uniform on
// reads, (5*row+2*half)%8 uniform on writes -> conflict-free both sides.
// 40 KB LDS + launch_bounds(256,3) -> 3 blocks/CU (12 waves/CU TLP, m114).
// One barrier per K-tile.  MODE 0: fp32 out.  MODE 1: QKV + fused RoPE.
#define LROW 40  // padded LDS row length (u16)
template <int MODE>
__global__ __launch_bounds__(256, 3) void gemm_rs(const u16* __restrict__ A,
                                                  const u16* __restrict__ B,
                                                  void* __restrict__ C0,
                                                  void* __restrict__ C1,
                                                  void* __restrict__ C2,
                                                  const float* __restrict__ fc,
                                                  const float* __restrict__ fs,
                                                  int M, int N, int K) {
    __shared__ u16 As[2 * 128 * LROW];
    __shared__ u16 Bs[2 * 128 * LROW];

    const int tid = threadIdx.x;
    const int lane = tid & 63;
    const int wid = tid >> 6;
    const int wr = wid >> 1;       // 0..1 (M)
    const int wc = wid & 1;        // 0..1 (N)
    const int quad = lane >> 4;
    const int l16 = lane & 15;

    // XCD-aware bijective block swizzle (nwg = 768 / 512, both % 8 == 0)
    const int nwg = gridDim.x * gridDim.y;
    int id = blockIdx.y * gridDim.x + blockIdx.x;
    int swz = (id & 7) * (nwg >> 3) + (id >> 3);
    const int bm = (swz / gridDim.x) * 128;
    const int bn = (swz % gridDim.x) * 128;

    f32x4 acc[4][4] = {};

    const int srow = tid >> 1;       // staging row 0..127
    const int shalf = tid & 1;       // 32B half of the 64B row

    // issue 4 global_load_dwordx4 (A 32B + B 32B) for tile t into regs
    auto gload = [&](int t, uint4* rA, uint4* rB) {
        const int k0 = t << 5;
        const size_t ar = (size_t)(bm + srow) * K + k0 + shalf * 16;
        rA[0] = *(const uint4*)&A[ar];
        rA[1] = *(const uint4*)&A[ar + 8];
        const size_t br = (size_t)(bn + srow) * K + k0 + shalf * 16;
        rB[0] = *(const uint4*)&B[br];
        rB[1] = *(const uint4*)&B[br + 8];
    };
    // write staged regs into LDS buffer buf (4 x ds_write_b128)
    auto lwrite = [&](int buf, const uint4* rA, const uint4* rB) {
        u16* pa = &As[buf * (128 * LROW) + srow * LROW + shalf * 16];
        *(uint4*)&pa[0] = rA[0];
        *(uint4*)&pa[8] = rA[1];
        u16* pb = &Bs[buf * (128 * LROW) + srow * LROW + shalf * 16];
        *(uint4*)&pb[0] = rB[0];
        *(uint4*)&pb[8] = rB[1];
    };
    // one K-tile of MFMA from LDS buffer buf: 8 ds_read_b128 + 16 MFMA
    const int wm = wr * 64;
    const int wn = wc * 64;
    auto compute = [&](int buf) {
        const u16* as = &As[buf * (128 * LROW)];
        const u16* bs = &Bs[buf * (128 * LROW)];
        bf16_8 a[4], b[4];
#pragma unroll
        for (int i = 0; i < 4; ++i)
            a[i] = *(const bf16_8*)&as[(wm + i * 16 + l16) * LROW + quad * 8];
#pragma unroll
        for (int j = 0; j < 4; ++j)
            b[j] = *(const bf16_8*)&bs[(wn + j * 16 + l16) * LROW + quad * 8];
        __builtin_amdgcn_s_setprio(1);
#pragma unroll
        for (int i = 0; i < 4; ++i)
#pragma unroll
            for (int j = 0; j < 4; ++j)
                acc[i][j] = __builtin_amdgcn_mfma_f32_16x16x32_bf16(a[i], b[j], acc[i][j], 0, 0, 0);
        __builtin_amdgcn_s_setprio(0);
    };

#define LGKM_BAR()                                             \
    asm volatile("s_waitcnt lgkmcnt(0)" ::: "memory");         \
    __builtin_amdgcn_s_barrier()

    const int NT = K >> 5;  // 128 for K=4096
    uint4 ra0[2], rb0[2], ra1[2], rb1[2];

    // prologue: tile0 -> regs -> LDS(buf0); tile1 -> regs (stays in flight)
    gload(0, ra0, rb0);
    lwrite(0, ra0, rb0);     // compiler reg-dep vmcnt drains tile0 only
    gload(1, ra1, rb1);
    LGKM_BAR();

    for (int t = 0; t < NT - 2; t += 2) {
        compute(0);                    // tile t      (buf0)
        gload(t + 2, ra0, rb0);        // issue t+2 early (ra0 free)
        lwrite(1, ra1, rb1);           // write t+1 -> buf1 (waits t+1's regs,
                                       //  leaves t+2's 4 loads in flight)
        LGKM_BAR();
        compute(1);                    // tile t+1    (buf1)
        gload(t + 3, ra1, rb1);        // issue t+3
        lwrite(0, ra0, rb0);           // write t+2 -> buf0
        LGKM_BAR();
    }
    // tail: buf0 holds tile NT-2, ra1 holds tile NT-1
    compute(0);
    lwrite(1, ra1, rb1);
    LGKM_BAR();
    compute(1);
#undef LGKM_BAR

    if (MODE == 0) {
        float* Cf = (float*)C0;
#pragma unroll
        for (int i = 0; i < 4; ++i)
#pragma unroll
            for (int j = 0; j < 4; ++j)
#pragma unroll
                for (int r = 0; r < 4; ++r)
                    Cf[(size_t)(bm + wm + i * 16 + quad * 4 + r) * N + (bn + wn + j * 16 + l16)] =
                        acc[i][j][r];
    } else {
        // QKV routing; bn is a multiple of 128 so the whole block takes one branch
        u16* Qb = (u16*)C0;
        u16* Kb = (u16*)C1;
        u16* Vt = (u16*)C2;
        if (bn < 5120) {
            const bool isQ = bn < 4096;
            const float osc = isQ ? QSCALE_LOG2E : 1.0f;
#pragma unroll
            for (int i = 0; i < 4; ++i)
#pragma unroll
                for (int j = 0; j < 4; ++j) {
                    int n = bn + wn + j * 16 + l16;
                    int pp = (n & 127) >> 1;
                    bool odd = (l16 & 1);
#pragma unroll
                    for (int r = 0; r < 4; ++r) {
                        int m = bm + wm + i * 16 + quad * 4 + r;
                        float v = acc[i][j][r];
                        float u = __shfl_xor(v, 1);
                        float c = fc[m * 64 + pp];
                        float s = fs[m * 64 + pp];
                        float o = (odd ? (u * s + v * c) : (v * c - u * s)) * osc;
                        if (isQ)
                            Qb[(size_t)m * 4096 + n] = f2bf(o);
                        else
                            Kb[(size_t)m * 1024 + (n - 4096)] = f2bf(o);
                    }
                }
        } else {
            // V range: store transposed (d-major), no rope
#pragma unroll
            for (int i = 0; i < 4; ++i)
#pragma unroll
                for (int j = 0; j < 4; ++j) {
                    int n = bn + wn + j * 16 + l16;
                    ushort4 o;
                    o.x = f2bf(acc[i][j][0]);
                    o.y = f2bf(acc[i][j][1]);
                    o.z = f2bf(acc[i][j][2]);
                    o.w = f2bf(acc[i][j][3]);
                    *(ushort4*)&Vt[(size_t)(n - 5120) * SEQ + (bm + wm + i * 16 + quad * 4)] = o;
                }
        }
    }
}

// ---------------- Flash attention, S^T formulation (unchanged) ----------------
__global__ __launch_bounds__(256, 4) void attn_k(const u16* __restrict__ Q,
                                                 const u16* __restrict__ Kb,
                                                 const u16* __restrict__ Vt,
                                                 u16* __restrict__ Y) {
    __shared__ u16 Ks[64 * 128];   // swizzled: 16B chunks, slot = c ^ (row&15)
    __shared__ u16 Vs[128 * 64];   // swizzled: 16B chunks, slot = c ^ (row&7)
    __shared__ u16 Ps[4 * 16 * 64];// per-wave 2 KB; 8B chunks, c' = c ^ ((l16&7)<<1)
    const int tid = threadIdx.x;
    const int lane = tid & 63;
    const int w = tid >> 6;
    const int quad = lane >> 4;
    const int l16 = lane & 15;
    const int id = blockIdx.x;
    const int qt = 31 - (id >> 5);   // LPT: longest blocks first
    const int h = id & 31;
    const int kvh = h >> 2;
    const size_t qrow0 = (size_t)qt * 64;

    bf16_8 qf[4];
#pragma unroll
    for (int ks = 0; ks < 4; ++ks)
        qf[ks] = *(const bf16_8*)&Q[(qrow0 + w * 16 + l16) * DIM + h * HD + ks * 32 + quad * 8];

    f32x4 po[8] = {};    // 16 x 128 unnormalized output accumulator
    float lsum = 0.f;    // per-lane partial row sum for q-row l16

    char* psbase = (char*)Ps + w * 2048 + l16 * 128;  // this lane's P row
    const int sw = (l16 & 7) << 1;                    // 8B-chunk swizzle

    for (int kt = 0; kt <= qt; ++kt) {
#pragma unroll
        for (int r = 0; r < 4; ++r) {
            int S = r * 256 + tid;  // 0..1023
            {
                int row = S >> 4, slot = S & 15;
                int chunk = slot ^ (row & 15);
                const char* g = (const char*)Kb +
                    (((size_t)kt * 64 + row) * 1024 + kvh * HD + chunk * 8) * 2;
                async16(g, (char*)Ks + S * 16);
            }
            {
                int row = S >> 3, slot = S & 7;
                int chunk = slot ^ (row & 7);
                const char* g = (const char*)Vt +
                    (((size_t)(kvh * HD + row)) * SEQ + kt * 64 + chunk * 8) * 2;
                async16(g, (char*)Vs + S * 16);
            }
        }
        __syncthreads();

        f32x4 sc[4] = {};
#pragma unroll
        for (int ks = 0; ks < 4; ++ks)
#pragma unroll
            for (int jb = 0; jb < 4; ++jb) {
                bf16_8 kb = *(const bf16_8*)&Ks[(jb * 16 + l16) * 128 + ((ks * 4 + quad) ^ l16) * 8];
                sc[jb] = __builtin_amdgcn_mfma_f32_16x16x32_bf16(kb, qf[ks], sc[jb], 0, 0, 0);
            }

        float pv[4][4];
#pragma unroll
        for (int jb = 0; jb < 4; ++jb)
#pragma unroll
            for (int r = 0; r < 4; ++r)
                pv[jb][r] = exp2f(sc[jb][r]);

        if (kt == qt) {  // wave-uniform: mask k > q on the diagonal tile
            int qloc = w * 16 + l16;
#pragma unroll
            for (int jb = 0; jb < 4; ++jb)
#pragma unroll
                for (int r = 0; r < 4; ++r)
                    if (jb * 16 + quad * 4 + r > qloc) pv[jb][r] = 0.f;
        }

#pragma unroll
        for (int jb = 0; jb < 4; ++jb) {
            lsum += (pv[jb][0] + pv[jb][1]) + (pv[jb][2] + pv[jb][3]);
            ushort4 pk;
            pk.x = f2bf(pv[jb][0]);
            pk.y = f2bf(pv[jb][1]);
            pk.z = f2bf(pv[jb][2]);
            pk.w = f2bf(pv[jb][3]);
            int c = jb * 4 + quad;
            *(ushort4*)(psbase + ((c ^ sw) << 3)) = pk;
        }

#pragma unroll
        for (int ks = 0; ks < 2; ++ks) {
            int c = ks * 8 + quad * 2;
            bf16_8 pf = *(const bf16_8*)(psbase + ((c ^ sw) << 3));
#pragma unroll
            for (int n = 0; n < 8; ++n) {
                bf16_8 vf = *(const bf16_8*)&Vs[(n * 16 + l16) * 64 + (((ks * 4 + quad) ^ (l16 & 7))) * 8];
                po[n] = __builtin_amdgcn_mfma_f32_16x16x32_bf16(pf, vf, po[n], 0, 0, 0);
            }
        }
        __syncthreads();
    }

    lsum += __shfl_xor(lsum, 16);
    lsum += __shfl_xor(lsum, 32);
    float inv = 1.f / lsum;
#pragma unroll
    for (int r = 0; r < 4; ++r) {
        float invr = __shfl(inv, quad * 4 + r);
        size_t row = qrow0 + w * 16 + quad * 4 + r;
#pragma unroll
        for (int n = 0; n < 8; ++n)
            Y[row * DIM + h * HD + n * 16 + l16] = f2bf(po[n][r] * invr);
    }
}

extern "C" void kernel_launch(void* const* d_in, const int* in_sizes, int n_in,
                              void* d_out, int out_size, void* d_ws, size_t ws_size,
                              hipStream_t stream) {
    const float* x  = (const float*)d_in[0];
    const float* wq = (const float*)d_in[1];
    const float* wk = (const float*)d_in[2];
    const float* wv = (const float*)d_in[3];
    const float* wo = (const float*)d_in[4];
    const float* fc = (const float*)d_in[5];
    const float* fs = (const float*)d_in[6];

    char* ws = (char*)d_ws;
    const size_t MB = 1u << 20;
    u16* xb    = (u16*)(ws);             // 2048x4096 bf16       (16 MB)
    u16* wqkvb = (u16*)(ws + 16 * MB);   // 6144x4096 (wq|wk|wv) (48 MB)
    u16* wob   = (u16*)(ws + 64 * MB);   // 4096x4096            (32 MB)
    u16* Qb    = (u16*)(ws + 96 * MB);   // 2048x4096            (16 MB)
    u16* Kb    = (u16*)(ws + 112 * MB);  // 2048x1024            (4 MB)
    u16* Vtb   = (u16*)(ws + 116 * MB);  // 1024x2048 (V^T)      (4 MB)
    u16* Yb    = (u16*)(ws + 120 * MB);  // 2048x4096            (16 MB)

    // single fused cast: [x | wq | wk | wv | wo] -> bf16 at ws[0..96MB)
    cast_all<<<49152, 256, 0, stream>>>(x, wq, wk, wv, wo, (u16*)ws);

    // fused QKV projection + RoPE (+ Q pre-scale incl. log2e) epilogue
    // 768 blocks = 3/CU exactly at launch_bounds(256,3)
    gemm_rs<1><<<dim3(48, 16), 256, 0, stream>>>(xb, wqkvb, Qb, Kb, Vtb, fc, fs,
                                                 2048, 6144, 4096);

    // attention (LPT-ordered 1D grid)
    attn_k<<<dim3(1024), 256, 0, stream>>>(Qb, Kb, Vtb, Yb);

    // output projection -> fp32 d_out
    gemm_rs<0><<<dim3(32, 16), 256, 0, stream>>>(Yb, wob, (float*)d_out, nullptr, nullptr,
                                                 nullptr, nullptr, 2048, 4096, 4096);
}

// Round 6
// 523.549 us; speedup vs baseline: 2.2886x; 2.2886x over previous
//
#include <hip/hip_runtime.h>
#include <hip/hip_bf16.h>
#include <stdint.h>

typedef unsigned short u16;
typedef __bf16 bf16_8 __attribute__((ext_vector_type(8)));
typedef float f32x4 __attribute__((ext_vector_type(4)));

#define SEQ 2048
#define DIM 4096
#define NH 32
#define NKV 8
#define HD 128
// 1/sqrt(128) * log2(e)  -- exp2-based softmax, scale folded into Q epilogue
#define QSCALE_LOG2E 0.12753785222167917f

__device__ inline u16 f2bf(float f) {
    unsigned int u = __float_as_uint(f);
    unsigned int r = (u + 0x7fffu + ((u >> 16) & 1u)) >> 16;
    return (u16)r;
}

__device__ inline void async16(const void* g, void* l) {
    __builtin_amdgcn_global_load_lds(
        (const __attribute__((address_space(1))) void*)g,
        (__attribute__((address_space(3))) void*)l, 16, 0, 0);
}

// ---------------- fused fp32 -> bf16 cast of all 5 tensors ----------------
__global__ __launch_bounds__(256) void cast_all(const float* __restrict__ x,
                                                const float* __restrict__ wq,
                                                const float* __restrict__ wk,
                                                const float* __restrict__ wv,
                                                const float* __restrict__ wo,
                                                u16* __restrict__ dst) {
    size_t i4 = (size_t)blockIdx.x * 256 + threadIdx.x;  // float4 group index
    size_t e = i4 * 4;                                   // element index
    const float* src;
    size_t off;  // segment start (elements)
    if (e < 8388608ull)       { src = x;  off = 0; }
    else if (e < 25165824ull) { src = wq; off = 8388608ull; }
    else if (e < 29360128ull) { src = wk; off = 25165824ull; }
    else if (e < 33554432ull) { src = wv; off = 29360128ull; }
    else                      { src = wo; off = 33554432ull; }
    float4 v = ((const float4*)src)[i4 - off / 4];
    ushort4 o;
    o.x = f2bf(v.x); o.y = f2bf(v.y); o.z = f2bf(v.z); o.w = f2bf(v.w);
    ((ushort4*)dst)[i4] = o;
}

// ======== reg-staged double-buffered GEMM: C = A[M,K] * B[N,K]^T (bf16) =====
// 128x128 tile, BK=32, 256 threads (4 waves, 2x2), wave tile 64x64, acc[4][4].
// Staging: global_load_dwordx4 -> NAMED uint4 VGPRs -> ds_write_b128.  All
// staging values are scalar named locals accessed only via macros (no lambdas,
// no address-taken locals -> no scratch; round-5 lesson / rule #20).  The
// load->write dependency is register-carried, so the compiler emits precise
// counted vmcnt (no LDS-DMA alias drain as with global_load_lds), and the
// next tiles' loads stay in flight across raw s_barrier.
// LDS layout (round-0 verified, 0 bank conflicts): per buffer 128 rows x 4
// chunks of 16B; chunk c of row r at slot c ^ ((r>>1)&3).  Read: lane
// (quad,l16) reads chunk quad of row (..+l16) at cs = quad ^ ((l16>>1)&3)
// -> each bank-group hit exactly 8x/wave (minimum).  Write: thread tid
// stages row tid>>1, chunks {2*(tid&1), 2*(tid&1)+1} -> also exact minimum.
// 32 KB LDS + launch_bounds(256,3) -> 3 blocks/CU (12 waves/CU TLP).
// One lgkmcnt(0)+s_barrier per K-tile; no vmcnt at barriers.
// MODE 0: fp32 out.  MODE 1: QKV + fused RoPE epilogue.
template <int MODE>
__global__ __launch_bounds__(256, 3) void gemm_rs(const u16* __restrict__ A,
                                                  const u16* __restrict__ B,
                                                  void* __restrict__ C0,
                                                  void* __restrict__ C1,
                                                  void* __restrict__ C2,
                                                  const float* __restrict__ fc,
                                                  const float* __restrict__ fs,
                                                  int M, int N, int K) {
    __shared__ u16 As[2 * 128 * 32];
    __shared__ u16 Bs[2 * 128 * 32];

    const int tid = threadIdx.x;
    const int lane = tid & 63;
    const int wid = tid >> 6;
    const int wr = wid >> 1;       // 0..1 (M)
    const int wc = wid & 1;        // 0..1 (N)
    const int quad = lane >> 4;
    const int l16 = lane & 15;

    // XCD-aware bijective block swizzle (nwg = 768 / 512, both % 8 == 0)
    const int nwg = gridDim.x * gridDim.y;
    int id = blockIdx.y * gridDim.x + blockIdx.x;
    int swz = (id & 7) * (nwg >> 3) + (id >> 3);
    const int bm = (swz / gridDim.x) * 128;
    const int bn = (swz % gridDim.x) * 128;

    f32x4 acc[4][4] = {};

    const int srow = tid >> 1;                      // staging row 0..127
    const int shalf = tid & 1;                      // which 32B half of 64B
    const int s0 = (shalf * 2) ^ ((srow >> 1) & 3); // swizzled chunk slots
    const int s1 = (shalf * 2 + 1) ^ ((srow >> 1) & 3);
    const size_t arowK = (size_t)(bm + srow) * K;
    const size_t browK = (size_t)(bn + srow) * K;
    const int cs = quad ^ ((l16 >> 1) & 3);         // read-side chunk slot
    const int wm = wr * 64;
    const int wn = wc * 64;

#define GLOAD(t, A0, A1, B0, B1)                                  \
    {                                                             \
        const size_t ko = (size_t)((t) << 5) + shalf * 16;        \
        A0 = *(const uint4*)&A[arowK + ko];                       \
        A1 = *(const uint4*)&A[arowK + ko + 8];                   \
        B0 = *(const uint4*)&B[browK + ko];                       \
        B1 = *(const uint4*)&B[browK + ko + 8];                   \
    }

#define LWRITE(buf, A0, A1, B0, B1)                               \
    {                                                             \
        u16* pa = &As[(buf) * 4096 + srow * 32];                  \
        *(uint4*)&pa[s0 * 8] = A0;                                \
        *(uint4*)&pa[s1 * 8] = A1;                                \
        u16* pb = &Bs[(buf) * 4096 + srow * 32];                  \
        *(uint4*)&pb[s0 * 8] = B0;                                \
        *(uint4*)&pb[s1 * 8] = B1;                                \
    }

#define COMPUTE(buf)                                                           \
    {                                                                          \
        const u16* as = &As[(buf) * 4096];                                     \
        const u16* bs = &Bs[(buf) * 4096];                                     \
        bf16_8 a[4], b[4];                                                     \
        _Pragma("unroll") for (int i = 0; i < 4; ++i)                          \
            a[i] = *(const bf16_8*)&as[(wm + i * 16 + l16) * 32 + cs * 8];     \
        _Pragma("unroll") for (int j = 0; j < 4; ++j)                          \
            b[j] = *(const bf16_8*)&bs[(wn + j * 16 + l16) * 32 + cs * 8];     \
        __builtin_amdgcn_s_setprio(1);                                         \
        _Pragma("unroll") for (int i = 0; i < 4; ++i)                          \
        _Pragma("unroll") for (int j = 0; j < 4; ++j)                          \
            acc[i][j] = __builtin_amdgcn_mfma_f32_16x16x32_bf16(a[i], b[j],    \
                                                                acc[i][j], 0, 0, 0); \
        __builtin_amdgcn_s_setprio(0);                                         \
    }

#define LGKM_BAR()                                                \
    asm volatile("s_waitcnt lgkmcnt(0)" ::: "memory");            \
    __builtin_amdgcn_s_barrier()

    const int NT = K >> 5;  // 128 for K=4096
    uint4 xa0, xa1, xb0, xb1;   // staging set X (even tiles)
    uint4 ya0, ya1, yb0, yb1;   // staging set Y (odd tiles)

    // prologue: tile0 -> regs -> LDS(buf0); tile1 -> regs (stays in flight)
    GLOAD(0, xa0, xa1, xb0, xb1);
    LWRITE(0, xa0, xa1, xb0, xb1);   // reg-dep vmcnt drains tile0 only
    GLOAD(1, ya0, ya1, yb0, yb1);
    LGKM_BAR();

    for (int t = 0; t < NT - 2; t += 2) {
        COMPUTE(0);                          // tile t      (buf0)
        GLOAD(t + 2, xa0, xa1, xb0, xb1);    // issue t+2 (X regs free)
        LWRITE(1, ya0, ya1, yb0, yb1);       // write t+1 -> buf1 (waits only
                                             //  t+1's regs; t+2 stays in flight)
        LGKM_BAR();
        COMPUTE(1);                          // tile t+1    (buf1)
        GLOAD(t + 3, ya0, ya1, yb0, yb1);    // issue t+3
        LWRITE(0, xa0, xa1, xb0, xb1);       // write t+2 -> buf0
        LGKM_BAR();
    }
    // tail: buf0 holds tile NT-2, Y regs hold tile NT-1
    COMPUTE(0);
    LWRITE(1, ya0, ya1, yb0, yb1);
    LGKM_BAR();
    COMPUTE(1);

#undef GLOAD
#undef LWRITE
#undef COMPUTE
#undef LGKM_BAR

    if (MODE == 0) {
        float* Cf = (float*)C0;
#pragma unroll
        for (int i = 0; i < 4; ++i)
#pragma unroll
            for (int j = 0; j < 4; ++j)
#pragma unroll
                for (int r = 0; r < 4; ++r)
                    Cf[(size_t)(bm + wm + i * 16 + quad * 4 + r) * N + (bn + wn + j * 16 + l16)] =
                        acc[i][j][r];
    } else {
        // QKV routing; bn is a multiple of 128 so the whole block takes one branch
        u16* Qb = (u16*)C0;
        u16* Kb = (u16*)C1;
        u16* Vt = (u16*)C2;
        if (bn < 5120) {
            const bool isQ = bn < 4096;
            const float osc = isQ ? QSCALE_LOG2E : 1.0f;
#pragma unroll
            for (int i = 0; i < 4; ++i)
#pragma unroll
                for (int j = 0; j < 4; ++j) {
                    int n = bn + wn + j * 16 + l16;
                    int pp = (n & 127) >> 1;
                    bool odd = (l16 & 1);
#pragma unroll
                    for (int r = 0; r < 4; ++r) {
                        int m = bm + wm + i * 16 + quad * 4 + r;
                        float v = acc[i][j][r];
                        float u = __shfl_xor(v, 1);
                        float c = fc[m * 64 + pp];
                        float s = fs[m * 64 + pp];
                        float o = (odd ? (u * s + v * c) : (v * c - u * s)) * osc;
                        if (isQ)
                            Qb[(size_t)m * 4096 + n] = f2bf(o);
                        else
                            Kb[(size_t)m * 1024 + (n - 4096)] = f2bf(o);
                    }
                }
        } else {
            // V range: store transposed (d-major), no rope
#pragma unroll
            for (int i = 0; i < 4; ++i)
#pragma unroll
                for (int j = 0; j < 4; ++j) {
                    int n = bn + wn + j * 16 + l16;
                    ushort4 o;
                    o.x = f2bf(acc[i][j][0]);
                    o.y = f2bf(acc[i][j][1]);
                    o.z = f2bf(acc[i][j][2]);
                    o.w = f2bf(acc[i][j][3]);
                    *(ushort4*)&Vt[(size_t)(n - 5120) * SEQ + (bm + wm + i * 16 + quad * 4)] = o;
                }
        }
    }
}

// ---------------- Flash attention, S^T formulation (unchanged) ----------------
__global__ __launch_bounds__(256, 4) void attn_k(const u16* __restrict__ Q,
                                                 const u16* __restrict__ Kb,
                                                 const u16* __restrict__ Vt,
                                                 u16* __restrict__ Y) {
    __shared__ u16 Ks[64 * 128];   // swizzled: 16B chunks, slot = c ^ (row&15)
    __shared__ u16 Vs[128 * 64];   // swizzled: 16B chunks, slot = c ^ (row&7)
    __shared__ u16 Ps[4 * 16 * 64];// per-wave 2 KB; 8B chunks, c' = c ^ ((l16&7)<<1)
    const int tid = threadIdx.x;
    const int lane = tid & 63;
    const int w = tid >> 6;
    const int quad = lane >> 4;
    const int l16 = lane & 15;
    const int id = blockIdx.x;
    const int qt = 31 - (id >> 5);   // LPT: longest blocks first
    const int h = id & 31;
    const int kvh = h >> 2;
    const size_t qrow0 = (size_t)qt * 64;

    bf16_8 qf[4];
#pragma unroll
    for (int ks = 0; ks < 4; ++ks)
        qf[ks] = *(const bf16_8*)&Q[(qrow0 + w * 16 + l16) * DIM + h * HD + ks * 32 + quad * 8];

    f32x4 po[8] = {};    // 16 x 128 unnormalized output accumulator
    float lsum = 0.f;    // per-lane partial row sum for q-row l16

    char* psbase = (char*)Ps + w * 2048 + l16 * 128;  // this lane's P row
    const int sw = (l16 & 7) << 1;                    // 8B-chunk swizzle

    for (int kt = 0; kt <= qt; ++kt) {
#pragma unroll
        for (int r = 0; r < 4; ++r) {
            int S = r * 256 + tid;  // 0..1023
            {
                int row = S >> 4, slot = S & 15;
                int chunk = slot ^ (row & 15);
                const char* g = (const char*)Kb +
                    (((size_t)kt * 64 + row) * 1024 + kvh * HD + chunk * 8) * 2;
                async16(g, (char*)Ks + S * 16);
            }
            {
                int row = S >> 3, slot = S & 7;
                int chunk = slot ^ (row & 7);
                const char* g = (const char*)Vt +
                    (((size_t)(kvh * HD + row)) * SEQ + kt * 64 + chunk * 8) * 2;
                async16(g, (char*)Vs + S * 16);
            }
        }
        __syncthreads();

        f32x4 sc[4] = {};
#pragma unroll
        for (int ks = 0; ks < 4; ++ks)
#pragma unroll
            for (int jb = 0; jb < 4; ++jb) {
                bf16_8 kb = *(const bf16_8*)&Ks[(jb * 16 + l16) * 128 + ((ks * 4 + quad) ^ l16) * 8];
                sc[jb] = __builtin_amdgcn_mfma_f32_16x16x32_bf16(kb, qf[ks], sc[jb], 0, 0, 0);
            }

        float pv[4][4];
#pragma unroll
        for (int jb = 0; jb < 4; ++jb)
#pragma unroll
            for (int r = 0; r < 4; ++r)
                pv[jb][r] = exp2f(sc[jb][r]);

        if (kt == qt) {  // wave-uniform: mask k > q on the diagonal tile
            int qloc = w * 16 + l16;
#pragma unroll
            for (int jb = 0; jb < 4; ++jb)
#pragma unroll
                for (int r = 0; r < 4; ++r)
                    if (jb * 16 + quad * 4 + r > qloc) pv[jb][r] = 0.f;
        }

#pragma unroll
        for (int jb = 0; jb < 4; ++jb) {
            lsum += (pv[jb][0] + pv[jb][1]) + (pv[jb][2] + pv[jb][3]);
            ushort4 pk;
            pk.x = f2bf(pv[jb][0]);
            pk.y = f2bf(pv[jb][1]);
            pk.z = f2bf(pv[jb][2]);
            pk.w = f2bf(pv[jb][3]);
            int c = jb * 4 + quad;
            *(ushort4*)(psbase + ((c ^ sw) << 3)) = pk;
        }

#pragma unroll
        for (int ks = 0; ks < 2; ++ks) {
            int c = ks * 8 + quad * 2;
            bf16_8 pf = *(const bf16_8*)(psbase + ((c ^ sw) << 3));
#pragma unroll
            for (int n = 0; n < 8; ++n) {
                bf16_8 vf = *(const bf16_8*)&Vs[(n * 16 + l16) * 64 + (((ks * 4 + quad) ^ (l16 & 7))) * 8];
                po[n] = __builtin_amdgcn_mfma_f32_16x16x32_bf16(pf, vf, po[n], 0, 0, 0);
            }
        }
        __syncthreads();
    }

    lsum += __shfl_xor(lsum, 16);
    lsum += __shfl_xor(lsum, 32);
    float inv = 1.f / lsum;
#pragma unroll
    for (int r = 0; r < 4; ++r) {
        float invr = __shfl(inv, quad * 4 + r);
        size_t row = qrow0 + w * 16 + quad * 4 + r;
#pragma unroll
        for (int n = 0; n < 8; ++n)
            Y[row * DIM + h * HD + n * 16 + l16] = f2bf(po[n][r] * invr);
    }
}

extern "C" void kernel_launch(void* const* d_in, const int* in_sizes, int n_in,
                              void* d_out, int out_size, void* d_ws, size_t ws_size,
                              hipStream_t stream) {
    const float* x  = (const float*)d_in[0];
    const float* wq = (const float*)d_in[1];
    const float* wk = (const float*)d_in[2];
    const float* wv = (const float*)d_in[3];
    const float* wo = (const float*)d_in[4];
    const float* fc = (const float*)d_in[5];
    const float* fs = (const float*)d_in[6];

    char* ws = (char*)d_ws;
    const size_t MB = 1u << 20;
    u16* xb    = (u16*)(ws);             // 2048x4096 bf16       (16 MB)
    u16* wqkvb = (u16*)(ws + 16 * MB);   // 6144x4096 (wq|wk|wv) (48 MB)
    u16* wob   = (u16*)(ws + 64 * MB);   // 4096x4096            (32 MB)
    u16* Qb    = (u16*)(ws + 96 * MB);   // 2048x4096            (16 MB)
    u16* Kb    = (u16*)(ws + 112 * MB);  // 2048x1024            (4 MB)
    u16* Vtb   = (u16*)(ws + 116 * MB);  // 1024x2048 (V^T)      (4 MB)
    u16* Yb    = (u16*)(ws + 120 * MB);  // 2048x4096            (16 MB)

    // single fused cast: [x | wq | wk | wv | wo] -> bf16 at ws[0..96MB)
    cast_all<<<49152, 256, 0, stream>>>(x, wq, wk, wv, wo, (u16*)ws);

    // fused QKV projection + RoPE (+ Q pre-scale incl. log2e) epilogue
    // 768 blocks = 3/CU exactly at launch_bounds(256,3)
    gemm_rs<1><<<dim3(48, 16), 256, 0, stream>>>(xb, wqkvb, Qb, Kb, Vtb, fc, fs,
                                                 2048, 6144, 4096);

    // attention (LPT-ordered 1D grid)
    attn_k<<<dim3(1024), 256, 0, stream>>>(Qb, Kb, Vtb, Yb);

    // output projection -> fp32 d_out
    gemm_rs<0><<<dim3(32, 16), 256, 0, stream>>>(Yb, wob, (float*)d_out, nullptr, nullptr,
                                                 nullptr, nullptr, 2048, 4096, 4096);
}

// Round 7
// 506.157 us; speedup vs baseline: 2.3672x; 1.0344x over previous
//
#include <hip/hip_runtime.h>
#include <hip/hip_bf16.h>
#include <stdint.h>

typedef unsigned short u16;
typedef __bf16 bf16_8 __attribute__((ext_vector_type(8)));
typedef float f32x4 __attribute__((ext_vector_type(4)));

#define SEQ 2048
#define DIM 4096
#define NH 32
#define NKV 8
#define HD 128
// 1/sqrt(128) * log2(e)  -- exp2-based softmax, scale folded into Q epilogue
#define QSCALE_LOG2E 0.12753785222167917f

__device__ inline u16 f2bf(float f) {
    unsigned int u = __float_as_uint(f);
    unsigned int r = (u + 0x7fffu + ((u >> 16) & 1u)) >> 16;
    return (u16)r;
}

__device__ inline void async16(const void* g, void* l) {
    __builtin_amdgcn_global_load_lds(
        (const __attribute__((address_space(1))) void*)g,
        (__attribute__((address_space(3))) void*)l, 16, 0, 0);
}

// ---------------- fused fp32 -> bf16 cast of all 5 tensors ----------------
__global__ __launch_bounds__(256) void cast_all(const float* __restrict__ x,
                                                const float* __restrict__ wq,
                                                const float* __restrict__ wk,
                                                const float* __restrict__ wv,
                                                const float* __restrict__ wo,
                                                u16* __restrict__ dst) {
    size_t i4 = (size_t)blockIdx.x * 256 + threadIdx.x;  // float4 group index
    size_t e = i4 * 4;                                   // element index
    const float* src;
    size_t off;  // segment start (elements)
    if (e < 8388608ull)       { src = x;  off = 0; }
    else if (e < 25165824ull) { src = wq; off = 8388608ull; }
    else if (e < 29360128ull) { src = wk; off = 25165824ull; }
    else if (e < 33554432ull) { src = wv; off = 29360128ull; }
    else                      { src = wo; off = 33554432ull; }
    float4 v = ((const float4*)src)[i4 - off / 4];
    ushort4 o;
    o.x = f2bf(v.x); o.y = f2bf(v.y); o.z = f2bf(v.z); o.w = f2bf(v.w);
    ((ushort4*)dst)[i4] = o;
}

// ======== reg-staged double-buffered GEMM: C = A[M,K] * B[N,K]^T (bf16) =====
// 128x128 tile, BK=32, 256 threads (4 waves, 2x2), wave tile 64x64, acc[4][4].
// Staging: global_load_dwordx4 -> NAMED uint4 VGPRs -> ds_write_b128 (no
// address-taken locals -> no scratch; round-5 lesson).  Register-carried
// load->write dep gives precise counted vmcnt; prefetch loads stay in flight
// across raw s_barrier.  LDS chunk-XOR layout: 0 bank conflicts (round-6 PMC).
// 32 KB LDS + launch_bounds(256,3) -> 3 blocks/CU.
// Block swizzle: 2D XCD partition.  HW dispatches consecutive ids round-robin
// over 8 XCDs (xcd = id&7); each XCD gets a contiguous (gy/2 x gx/4) tile
// sub-grid, so per-XCD L2 fill = A/2 + B/4 (QKV: 8+12=20 MB -> ~160 MB total
// vs 405 MB measured for the 1D row-sliced swizzle = the round-6 wall).
// MODE 0: fp32 out.  MODE 1: QKV + fused RoPE epilogue.
template <int MODE>
__global__ __launch_bounds__(256, 3) void gemm_rs(const u16* __restrict__ A,
                                                  const u16* __restrict__ B,
                                                  void* __restrict__ C0,
                                                  void* __restrict__ C1,
                                                  void* __restrict__ C2,
                                                  const float* __restrict__ fc,
                                                  const float* __restrict__ fs,
                                                  int M, int N, int K) {
    __shared__ u16 As[2 * 128 * 32];
    __shared__ u16 Bs[2 * 128 * 32];

    const int tid = threadIdx.x;
    const int lane = tid & 63;
    const int wid = tid >> 6;
    const int wr = wid >> 1;       // 0..1 (M)
    const int wc = wid & 1;        // 0..1 (N)
    const int quad = lane >> 4;
    const int l16 = lane & 15;

    // ---- 2D XCD partition (bijective; gy%2==0 and gx%4==0 for both grids).
    // xcd 2x4 layout: per-XCD sub-grid is (gy/2) bm-tiles x (gx/4) bn-tiles,
    // bm-fastest so blocks sharing a B-tile are id-adjacent.
    const int gx = gridDim.x, gy = gridDim.y;
    int id = blockIdx.y * gx + blockIdx.x;
    const int xcd = id & 7;
    const int j = id >> 3;
    const int hy = gy >> 1;
    const int jm = j % hy;
    const int jn = j / hy;
    const int bm = ((xcd >> 2) * hy + jm) * 128;
    const int bn = ((xcd & 3) * (gx >> 2) + jn) * 128;

    f32x4 acc[4][4] = {};

    const int srow = tid >> 1;                      // staging row 0..127
    const int shalf = tid & 1;                      // which 32B half of 64B
    const int s0 = (shalf * 2) ^ ((srow >> 1) & 3); // swizzled chunk slots
    const int s1 = (shalf * 2 + 1) ^ ((srow >> 1) & 3);
    const size_t arowK = (size_t)(bm + srow) * K;
    const size_t browK = (size_t)(bn + srow) * K;
    const int cs = quad ^ ((l16 >> 1) & 3);         // read-side chunk slot
    const int wm = wr * 64;
    const int wn = wc * 64;

#define GLOAD(t, A0, A1, B0, B1)                                  \
    {                                                             \
        const size_t ko = (size_t)((t) << 5) + shalf * 16;        \
        A0 = *(const uint4*)&A[arowK + ko];                       \
        A1 = *(const uint4*)&A[arowK + ko + 8];                   \
        B0 = *(const uint4*)&B[browK + ko];                       \
        B1 = *(const uint4*)&B[browK + ko + 8];                   \
    }

#define LWRITE(buf, A0, A1, B0, B1)                               \
    {                                                             \
        u16* pa = &As[(buf) * 4096 + srow * 32];                  \
        *(uint4*)&pa[s0 * 8] = A0;                                \
        *(uint4*)&pa[s1 * 8] = A1;                                \
        u16* pb = &Bs[(buf) * 4096 + srow * 32];                  \
        *(uint4*)&pb[s0 * 8] = B0;                                \
        *(uint4*)&pb[s1 * 8] = B1;                                \
    }

#define COMPUTE(buf)                                                           \
    {                                                                          \
        const u16* as = &As[(buf) * 4096];                                     \
        const u16* bs = &Bs[(buf) * 4096];                                     \
        bf16_8 a[4], b[4];                                                     \
        _Pragma("unroll") for (int i = 0; i < 4; ++i)                          \
            a[i] = *(const bf16_8*)&as[(wm + i * 16 + l16) * 32 + cs * 8];     \
        _Pragma("unroll") for (int j2 = 0; j2 < 4; ++j2)                       \
            b[j2] = *(const bf16_8*)&bs[(wn + j2 * 16 + l16) * 32 + cs * 8];   \
        __builtin_amdgcn_s_setprio(1);                                         \
        _Pragma("unroll") for (int i = 0; i < 4; ++i)                          \
        _Pragma("unroll") for (int j2 = 0; j2 < 4; ++j2)                       \
            acc[i][j2] = __builtin_amdgcn_mfma_f32_16x16x32_bf16(a[i], b[j2],  \
                                                                acc[i][j2], 0, 0, 0); \
        __builtin_amdgcn_s_setprio(0);                                         \
    }

#define LGKM_BAR()                                                \
    asm volatile("s_waitcnt lgkmcnt(0)" ::: "memory");            \
    __builtin_amdgcn_s_barrier()

    const int NT = K >> 5;  // 128 for K=4096
    uint4 xa0, xa1, xb0, xb1;   // staging set X (even tiles)
    uint4 ya0, ya1, yb0, yb1;   // staging set Y (odd tiles)

    // prologue: tile0 -> regs -> LDS(buf0); tile1 -> regs (stays in flight)
    GLOAD(0, xa0, xa1, xb0, xb1);
    LWRITE(0, xa0, xa1, xb0, xb1);   // reg-dep vmcnt drains tile0 only
    GLOAD(1, ya0, ya1, yb0, yb1);
    LGKM_BAR();

    for (int t = 0; t < NT - 2; t += 2) {
        COMPUTE(0);                          // tile t      (buf0)
        GLOAD(t + 2, xa0, xa1, xb0, xb1);    // issue t+2 (X regs free)
        LWRITE(1, ya0, ya1, yb0, yb1);       // write t+1 -> buf1 (waits only
                                             //  t+1's regs; t+2 stays in flight)
        LGKM_BAR();
        COMPUTE(1);                          // tile t+1    (buf1)
        GLOAD(t + 3, ya0, ya1, yb0, yb1);    // issue t+3
        LWRITE(0, xa0, xa1, xb0, xb1);       // write t+2 -> buf0
        LGKM_BAR();
    }
    // tail: buf0 holds tile NT-2, Y regs hold tile NT-1
    COMPUTE(0);
    LWRITE(1, ya0, ya1, yb0, yb1);
    LGKM_BAR();
    COMPUTE(1);

#undef GLOAD
#undef LWRITE
#undef COMPUTE
#undef LGKM_BAR

    if (MODE == 0) {
        float* Cf = (float*)C0;
#pragma unroll
        for (int i = 0; i < 4; ++i)
#pragma unroll
            for (int j2 = 0; j2 < 4; ++j2)
#pragma unroll
                for (int r = 0; r < 4; ++r)
                    Cf[(size_t)(bm + wm + i * 16 + quad * 4 + r) * N + (bn + wn + j2 * 16 + l16)] =
                        acc[i][j2][r];
    } else {
        // QKV routing; bn is a multiple of 128 so the whole block takes one branch
        u16* Qb = (u16*)C0;
        u16* Kb = (u16*)C1;
        u16* Vt = (u16*)C2;
        if (bn < 5120) {
            const bool isQ = bn < 4096;
            const float osc = isQ ? QSCALE_LOG2E : 1.0f;
#pragma unroll
            for (int i = 0; i < 4; ++i)
#pragma unroll
                for (int j2 = 0; j2 < 4; ++j2) {
                    int n = bn + wn + j2 * 16 + l16;
                    int pp = (n & 127) >> 1;
                    bool odd = (l16 & 1);
#pragma unroll
                    for (int r = 0; r < 4; ++r) {
                        int m = bm + wm + i * 16 + quad * 4 + r;
                        float v = acc[i][j2][r];
                        float u = __shfl_xor(v, 1);
                        float c = fc[m * 64 + pp];
                        float s = fs[m * 64 + pp];
                        float o = (odd ? (u * s + v * c) : (v * c - u * s)) * osc;
                        if (isQ)
                            Qb[(size_t)m * 4096 + n] = f2bf(o);
                        else
                            Kb[(size_t)m * 1024 + (n - 4096)] = f2bf(o);
                    }
                }
        } else {
            // V range: store transposed (d-major), no rope
#pragma unroll
            for (int i = 0; i < 4; ++i)
#pragma unroll
                for (int j2 = 0; j2 < 4; ++j2) {
                    int n = bn + wn + j2 * 16 + l16;
                    ushort4 o;
                    o.x = f2bf(acc[i][j2][0]);
                    o.y = f2bf(acc[i][j2][1]);
                    o.z = f2bf(acc[i][j2][2]);
                    o.w = f2bf(acc[i][j2][3]);
                    *(ushort4*)&Vt[(size_t)(n - 5120) * SEQ + (bm + wm + i * 16 + quad * 4)] = o;
                }
        }
    }
}

// ---------------- Flash attention, S^T formulation (unchanged) ----------------
__global__ __launch_bounds__(256, 4) void attn_k(const u16* __restrict__ Q,
                                                 const u16* __restrict__ Kb,
                                                 const u16* __restrict__ Vt,
                                                 u16* __restrict__ Y) {
    __shared__ u16 Ks[64 * 128];   // swizzled: 16B chunks, slot = c ^ (row&15)
    __shared__ u16 Vs[128 * 64];   // swizzled: 16B chunks, slot = c ^ (row&7)
    __shared__ u16 Ps[4 * 16 * 64];// per-wave 2 KB; 8B chunks, c' = c ^ ((l16&7)<<1)
    const int tid = threadIdx.x;
    const int lane = tid & 63;
    const int w = tid >> 6;
    const int quad = lane >> 4;
    const int l16 = lane & 15;
    const int id = blockIdx.x;
    const int qt = 31 - (id >> 5);   // LPT: longest blocks first
    const int h = id & 31;
    const int kvh = h >> 2;
    const size_t qrow0 = (size_t)qt * 64;

    bf16_8 qf[4];
#pragma unroll
    for (int ks = 0; ks < 4; ++ks)
        qf[ks] = *(const bf16_8*)&Q[(qrow0 + w * 16 + l16) * DIM + h * HD + ks * 32 + quad * 8];

    f32x4 po[8] = {};    // 16 x 128 unnormalized output accumulator
    float lsum = 0.f;    // per-lane partial row sum for q-row l16

    char* psbase = (char*)Ps + w * 2048 + l16 * 128;  // this lane's P row
    const int sw = (l16 & 7) << 1;                    // 8B-chunk swizzle

    for (int kt = 0; kt <= qt; ++kt) {
#pragma unroll
        for (int r = 0; r < 4; ++r) {
            int S = r * 256 + tid;  // 0..1023
            {
                int row = S >> 4, slot = S & 15;
                int chunk = slot ^ (row & 15);
                const char* g = (const char*)Kb +
                    (((size_t)kt * 64 + row) * 1024 + kvh * HD + chunk * 8) * 2;
                async16(g, (char*)Ks + S * 16);
            }
            {
                int row = S >> 3, slot = S & 7;
                int chunk = slot ^ (row & 7);
                const char* g = (const char*)Vt +
                    (((size_t)(kvh * HD + row)) * SEQ + kt * 64 + chunk * 8) * 2;
                async16(g, (char*)Vs + S * 16);
            }
        }
        __syncthreads();

        f32x4 sc[4] = {};
#pragma unroll
        for (int ks = 0; ks < 4; ++ks)
#pragma unroll
            for (int jb = 0; jb < 4; ++jb) {
                bf16_8 kb = *(const bf16_8*)&Ks[(jb * 16 + l16) * 128 + ((ks * 4 + quad) ^ l16) * 8];
                sc[jb] = __builtin_amdgcn_mfma_f32_16x16x32_bf16(kb, qf[ks], sc[jb], 0, 0, 0);
            }

        float pv[4][4];
#pragma unroll
        for (int jb = 0; jb < 4; ++jb)
#pragma unroll
            for (int r = 0; r < 4; ++r)
                pv[jb][r] = exp2f(sc[jb][r]);

        if (kt == qt) {  // wave-uniform: mask k > q on the diagonal tile
            int qloc = w * 16 + l16;
#pragma unroll
            for (int jb = 0; jb < 4; ++jb)
#pragma unroll
                for (int r = 0; r < 4; ++r)
                    if (jb * 16 + quad * 4 + r > qloc) pv[jb][r] = 0.f;
        }

#pragma unroll
        for (int jb = 0; jb < 4; ++jb) {
            lsum += (pv[jb][0] + pv[jb][1]) + (pv[jb][2] + pv[jb][3]);
            ushort4 pk;
            pk.x = f2bf(pv[jb][0]);
            pk.y = f2bf(pv[jb][1]);
            pk.z = f2bf(pv[jb][2]);
            pk.w = f2bf(pv[jb][3]);
            int c = jb * 4 + quad;
            *(ushort4*)(psbase + ((c ^ sw) << 3)) = pk;
        }

#pragma unroll
        for (int ks = 0; ks < 2; ++ks) {
            int c = ks * 8 + quad * 2;
            bf16_8 pf = *(const bf16_8*)(psbase + ((c ^ sw) << 3));
#pragma unroll
            for (int n = 0; n < 8; ++n) {
                bf16_8 vf = *(const bf16_8*)&Vs[(n * 16 + l16) * 64 + (((ks * 4 + quad) ^ (l16 & 7))) * 8];
                po[n] = __builtin_amdgcn_mfma_f32_16x16x32_bf16(pf, vf, po[n], 0, 0, 0);
            }
        }
        __syncthreads();
    }

    lsum += __shfl_xor(lsum, 16);
    lsum += __shfl_xor(lsum, 32);
    float inv = 1.f / lsum;
#pragma unroll
    for (int r = 0; r < 4; ++r) {
        float invr = __shfl(inv, quad * 4 + r);
        size_t row = qrow0 + w * 16 + quad * 4 + r;
#pragma unroll
        for (int n = 0; n < 8; ++n)
            Y[row * DIM + h * HD + n * 16 + l16] = f2bf(po[n][r] * invr);
    }
}

extern "C" void kernel_launch(void* const* d_in, const int* in_sizes, int n_in,
                              void* d_out, int out_size, void* d_ws, size_t ws_size,
                              hipStream_t stream) {
    const float* x  = (const float*)d_in[0];
    const float* wq = (const float*)d_in[1];
    const float* wk = (const float*)d_in[2];
    const float* wv = (const float*)d_in[3];
    const float* wo = (const float*)d_in[4];
    const float* fc = (const float*)d_in[5];
    const float* fs = (const float*)d_in[6];

    char* ws = (char*)d_ws;
    const size_t MB = 1u << 20;
    u16* xb    = (u16*)(ws);             // 2048x4096 bf16       (16 MB)
    u16* wqkvb = (u16*)(ws + 16 * MB);   // 6144x4096 (wq|wk|wv) (48 MB)
    u16* wob   = (u16*)(ws + 64 * MB);   // 4096x4096            (32 MB)
    u16* Qb    = (u16*)(ws + 96 * MB);   // 2048x4096            (16 MB)
    u16* Kb    = (u16*)(ws + 112 * MB);  // 2048x1024            (4 MB)
    u16* Vtb   = (u16*)(ws + 116 * MB);  // 1024x2048 (V^T)      (4 MB)
    u16* Yb    = (u16*)(ws + 120 * MB);  // 2048x4096            (16 MB)

    // single fused cast: [x | wq | wk | wv | wo] -> bf16 at ws[0..96MB)
    cast_all<<<49152, 256, 0, stream>>>(x, wq, wk, wv, wo, (u16*)ws);

    // fused QKV projection + RoPE (+ Q pre-scale incl. log2e) epilogue
    // 768 blocks = 3/CU exactly at launch_bounds(256,3)
    gemm_rs<1><<<dim3(48, 16), 256, 0, stream>>>(xb, wqkvb, Qb, Kb, Vtb, fc, fs,
                                                 2048, 6144, 4096);

    // attention (LPT-ordered 1D grid)
    attn_k<<<dim3(1024), 256, 0, stream>>>(Qb, Kb, Vtb, Yb);

    // output projection -> fp32 d_out
    gemm_rs<0><<<dim3(32, 16), 256, 0, stream>>>(Yb, wob, (float*)d_out, nullptr, nullptr,
                                                 nullptr, nullptr, 2048, 4096, 4096);
}